// Round 1
// baseline (147.668 us; speedup 1.0000x reference)
//
#include <hip/hip_runtime.h>

// N=65536, D_OUT=128, D_LAT=64, D_Z=64. Streaming multi-reduction.
// R3/R4: two access structures both plateau at ~3.1 TB/s combined service;
// half the HBM traffic during vde_main is writeback of restore/poison-dirtied
// cache lines evicted by our allocating reads (nt hint alone doesn't stop
// allocation -> R5 neutral).
// R6 probe: full cache-bypass loads (sc0 sc1 nt, system scope, no allocate)
// -> no dirty-victim evictions -> no concurrent writeback -> pure 134 MB read.
constexpr int N_ROWS  = 65536;
constexpr int THREADS = 256;
constexpr int B_MSE = 1024, B_KL = 512, B_Z = 512;
constexpr int BLOCKS = B_MSE + B_KL + B_Z;      // 2048
constexpr int F4_BLK = 2048;                    // float4s per block per array
constexpr int IT     = F4_BLK / THREADS;        // 8 iters/thread

constexpr int NVAL = 324;   // [0]=recon, [1]=kl, [2+st*64+col] (5*64)
constexpr int NREP = 64;    // replicas: contention <= 16 per address

typedef float f4v __attribute__((ext_vector_type(4)));

// Streaming load: system scope + non-temporal => bypass/no-allocate in
// L1/L2/L3. Coherence point services dirty data, so correctness is HW-held.
__device__ __forceinline__ f4v sload(const f4v* p) {
    f4v r;
    asm volatile("global_load_dwordx4 %0, %1, off sc0 sc1 nt"
                 : "=v"(r) : "v"(p));
    return r;
}
// Compiler doesn't track inline-asm loads: wait + sched fence (rule: hipcc
// hoists register-only consumers past inline-asm waitcnt without the fence).
__device__ __forceinline__ void sload_wait() {
    asm volatile("s_waitcnt vmcnt(0)" ::: "memory");
    __builtin_amdgcn_sched_barrier(0);
}

// ws layout (floats): [r*NVAL + v], r in [0,64). memset to 0 each call.

__global__ __launch_bounds__(THREADS) void vde_main(
    const f4v* __restrict__ target,
    const f4v* __restrict__ output,
    const f4v* __restrict__ mean,
    const f4v* __restrict__ logvar,
    const f4v* __restrict__ zt,
    const f4v* __restrict__ ztau,
    float* __restrict__ ws)
{
    const int lane = threadIdx.x & 63;
    const int wave = threadIdx.x >> 6;
    float* rep = ws + (blockIdx.x & (NREP - 1)) * NVAL;

    __shared__ float ssc[4];                 // scalar cross-wave (MSE/KL)
    __shared__ float sred[4][16][20];        // column stats cross-wave (Z)

    if (blockIdx.x < B_MSE) {
        // ---------------- MSE: sum (o - t)^2 ------------------------------
        const int base = blockIdx.x * F4_BLK + threadIdx.x;
        f4v o[IT], t[IT];
        #pragma unroll
        for (int it = 0; it < IT; ++it) {
            o[it] = sload(&output[base + it * THREADS]);
            t[it] = sload(&target[base + it * THREADS]);
        }
        sload_wait();
        float recon = 0.f;
        #pragma unroll
        for (int it = 0; it < IT; ++it) {
            f4v d = o[it] - t[it];
            recon += d[0]*d[0] + d[1]*d[1] + d[2]*d[2] + d[3]*d[3];
        }
        #pragma unroll
        for (int m = 32; m >= 1; m >>= 1) recon += __shfl_xor(recon, m);
        if (lane == 0) ssc[wave] = recon;
        __syncthreads();
        if (threadIdx.x == 0)
            atomicAdd(&rep[0], ssc[0] + ssc[1] + ssc[2] + ssc[3]);

    } else if (blockIdx.x < B_MSE + B_KL) {
        // ---------------- KL: sum (lv - e^lv - m^2 + 1) -------------------
        const int base = (blockIdx.x - B_MSE) * F4_BLK + threadIdx.x;
        f4v lv[IT], mm[IT];
        #pragma unroll
        for (int it = 0; it < IT; ++it) {
            lv[it] = sload(&logvar[base + it * THREADS]);
            mm[it] = sload(&mean[base + it * THREADS]);
        }
        sload_wait();
        float kls = 0.f;
        #pragma unroll
        for (int it = 0; it < IT; ++it) {
            kls += (lv[it][0] - __expf(lv[it][0]) - mm[it][0]*mm[it][0] + 1.f)
                 + (lv[it][1] - __expf(lv[it][1]) - mm[it][1]*mm[it][1] + 1.f)
                 + (lv[it][2] - __expf(lv[it][2]) - mm[it][2]*mm[it][2] + 1.f)
                 + (lv[it][3] - __expf(lv[it][3]) - mm[it][3]*mm[it][3] + 1.f);
        }
        #pragma unroll
        for (int m = 32; m >= 1; m >>= 1) kls += __shfl_xor(kls, m);
        if (lane == 0) ssc[wave] = kls;
        __syncthreads();
        if (threadIdx.x == 0)
            atomicAdd(&rep[1], ssc[0] + ssc[1] + ssc[2] + ssc[3]);

    } else {
        // ---------------- Z column stats ----------------------------------
        // f = zb*2048 + it*256 + tid -> f%16 == tid%16: each thread owns the
        // fixed 4-column group g = tid&15 (cols 4g..4g+3).
        const int base = (blockIdx.x - B_MSE - B_KL) * F4_BLK + threadIdx.x;
        f4v a[IT], b[IT];
        #pragma unroll
        for (int it = 0; it < IT; ++it) {
            a[it] = sload(&zt[base + it * THREADS]);
            b[it] = sload(&ztau[base + it * THREADS]);
        }
        sload_wait();
        float s_t[4] = {0,0,0,0}, s_t2[4] = {0,0,0,0};
        float s_a[4] = {0,0,0,0}, s_a2[4] = {0,0,0,0}, s_c[4] = {0,0,0,0};
        #pragma unroll
        for (int it = 0; it < IT; ++it) {
            #pragma unroll
            for (int e = 0; e < 4; ++e) {
                s_t[e]  += a[it][e];          s_a[e]  += b[it][e];
                s_t2[e] += a[it][e]*a[it][e]; s_a2[e] += b[it][e]*b[it][e];
                s_c[e]  += a[it][e]*b[it][e];
            }
        }
        float vals[20];
        #pragma unroll
        for (int e = 0; e < 4; ++e) {
            vals[e*5+0] = s_t[e];  vals[e*5+1] = s_a[e];
            vals[e*5+2] = s_t2[e]; vals[e*5+3] = s_a2[e];
            vals[e*5+4] = s_c[e];
        }
        #pragma unroll
        for (int v = 0; v < 20; ++v) {
            vals[v] += __shfl_xor(vals[v], 16);
            vals[v] += __shfl_xor(vals[v], 32);
        }
        if (lane < 16) {
            #pragma unroll
            for (int v = 0; v < 20; ++v) sred[wave][lane][v] = vals[v];
        }
        __syncthreads();
        for (int i = threadIdx.x; i < 320; i += THREADS) {
            const int g = i / 20, v = i % 20;
            const float s = sred[0][g][v] + sred[1][g][v]
                          + sred[2][g][v] + sred[3][g][v];
            const int e = v / 5, st = v % 5;
            atomicAdd(&rep[2 + st * 64 + (g * 4 + e)], s);
        }
    }
}

// Collapse 64 replicas + finalize, one block.
__global__ __launch_bounds__(256) void vde_tail(
    const float* __restrict__ ws, float* __restrict__ out)
{
    __shared__ float sums[NVAL];
    for (int j = threadIdx.x; j < NVAL; j += 256) {
        float s = 0.f;
        #pragma unroll
        for (int r = 0; r < NREP; ++r) s += ws[r * NVAL + j];
        sums[j] = s;
    }
    __syncthreads();

    if (threadIdx.x < 64) {
        const int j = threadIdx.x;          // column 0..63
        const float Nf = (float)N_ROWS;
        const float sum_t  = sums[2 + 0*64 + j];
        const float sum_a  = sums[2 + 1*64 + j];
        const float sum_t2 = sums[2 + 2*64 + j];
        const float sum_a2 = sums[2 + 3*64 + j];
        const float sum_c  = sums[2 + 4*64 + j];

        const float mu_t = sum_t / Nf, mu_a = sum_a / Nf;
        float diag = sum_c - Nf * mu_t * mu_a;
        const float var_t = (sum_t2 - Nf * mu_t * mu_t) / (Nf - 1.f);
        const float var_a = (sum_a2 - Nf * mu_a * mu_a) / (Nf - 1.f);
        float sp = sqrtf(var_t) * sqrtf(var_a);

        #pragma unroll
        for (int m = 32; m >= 1; m >>= 1) {
            diag += __shfl_xor(diag, m);
            sp   += __shfl_xor(sp, m);
        }
        if (j == 0) {
            const float recon_f = sums[0] / (Nf * 128.f);
            const float kl_f    = -0.5f * sums[1] / Nf;
            out[0] = recon_f + kl_f - (diag / Nf) / sp;
        }
    }
}

extern "C" void kernel_launch(void* const* d_in, const int* in_sizes, int n_in,
                              void* d_out, int out_size, void* d_ws, size_t ws_size,
                              hipStream_t stream) {
    const f4v* target = (const f4v*)d_in[0];
    const f4v* output = (const f4v*)d_in[1];
    const f4v* mean   = (const f4v*)d_in[2];
    const f4v* logvar = (const f4v*)d_in[3];
    const f4v* zt     = (const f4v*)d_in[4];
    const f4v* ztau   = (const f4v*)d_in[5];
    float* ws  = (float*)d_ws;
    float* out = (float*)d_out;

    // zero the replicated accumulators (ws re-poisoned to 0xAA each call)
    hipMemsetAsync(ws, 0, NREP * NVAL * sizeof(float), stream);
    vde_main<<<BLOCKS, THREADS, 0, stream>>>(target, output, mean, logvar, zt, ztau, ws);
    vde_tail<<<1, 256, 0, stream>>>(ws, out);
}